// Round 1
// baseline (648.105 us; speedup 1.0000x reference)
//
#include <hip/hip_runtime.h>
#include <hip/hip_bf16.h>

// DeepseekV4 shared expert: int8 dynamic-quant SwiGLU MLP.
// T=8192 tokens, H=4096 hidden, I=2048 intermediate (derived from in_sizes).
// Pipeline: wconv x3 -> quant_x -> gemm1(gate+up fused, silu, clip, bf16)
//           -> quant_inter -> gemm2 -> out fp32.
//
// GEMMs use a counted-vmcnt triple-buffered pipeline (no vmcnt(0) drain in
// the steady-state loop), XOR bank-swizzled LDS (2-way, free), and setprio
// around the MFMA cluster. Raw s_barrier + manual s_waitcnt only.

typedef __attribute__((ext_vector_type(4))) int i32x4;

__device__ __forceinline__ void async16(void* lds, const void* g) {
  __builtin_amdgcn_global_load_lds(
      (const __attribute__((address_space(1))) void*)g,
      (__attribute__((address_space(3))) void*)lds, 16, 0, 0);
}

__device__ __forceinline__ i32x4 mfma_i8(i32x4 a, i32x4 b, i32x4 c) {
  return __builtin_amdgcn_mfma_i32_16x16x64_i8(a, b, c, 0, 0, 0);
}

// fp32 -> bf16 round-to-nearest-even, back to fp32
__device__ __forceinline__ float bf16_rne_f(float f) {
  unsigned u = __float_as_uint(f);
  u += 0x7fffu + ((u >> 16) & 1u);
  return __uint_as_float(u & 0xffff0000u);
}

__device__ __forceinline__ unsigned short bf16_bits(float f) {
  unsigned u = __float_as_uint(f);
  u += 0x7fffu + ((u >> 16) & 1u);
  return (unsigned short)(u >> 16);
}

__device__ __forceinline__ float bf16_to_f(unsigned short h) {
  return __uint_as_float(((unsigned)h) << 16);
}

#define BARRIER __builtin_amdgcn_s_barrier()
#define WAIT_VM6 asm volatile("s_waitcnt vmcnt(6) lgkmcnt(0)" ::: "memory")
#define WAIT_VM4 asm volatile("s_waitcnt vmcnt(4) lgkmcnt(0)" ::: "memory")
#define WAIT_VM0 asm volatile("s_waitcnt vmcnt(0) lgkmcnt(0)" ::: "memory")

// ---------------- weight fp32 (int8-valued) -> int8 ----------------
__global__ void wconv_kernel(const float* __restrict__ w,
                             signed char* __restrict__ wq, int n) {
  int i = (blockIdx.x * 256 + threadIdx.x) * 4;
  if (i >= n) return;
  float4 f = *(const float4*)(w + i);
  signed char c[4] __attribute__((aligned(4)));
  c[0] = (signed char)(int)rintf(f.x);
  c[1] = (signed char)(int)rintf(f.y);
  c[2] = (signed char)(int)rintf(f.z);
  c[3] = (signed char)(int)rintf(f.w);
  *(int*)(wq + i) = *(const int*)c;
}

// ---------------- per-token quant of x (both gate & up smoothing) ----------------
__global__ __launch_bounds__(256) void quant_x_kernel(
    const float* __restrict__ x, const float* __restrict__ invg,
    const float* __restrict__ invu, signed char* __restrict__ qg,
    signed char* __restrict__ qu, float* __restrict__ sg,
    float* __restrict__ su, int H) {
  const int t = blockIdx.x, tid = threadIdx.x;
  const float* xr = x + (size_t)t * H;
  const int c0 = tid * 16;  // 256 threads * 16 = 4096 = H
  float xg[16], xu[16];
  float mg = 0.f, mu = 0.f;
#pragma unroll
  for (int v = 0; v < 4; ++v) {
    float4 f = *(const float4*)(xr + c0 + v * 4);
    float4 ig = *(const float4*)(invg + c0 + v * 4);
    float4 iu = *(const float4*)(invu + c0 + v * 4);
    float b0 = bf16_rne_f(f.x), b1 = bf16_rne_f(f.y);
    float b2 = bf16_rne_f(f.z), b3 = bf16_rne_f(f.w);
    xg[v * 4 + 0] = b0 * ig.x; xg[v * 4 + 1] = b1 * ig.y;
    xg[v * 4 + 2] = b2 * ig.z; xg[v * 4 + 3] = b3 * ig.w;
    xu[v * 4 + 0] = b0 * iu.x; xu[v * 4 + 1] = b1 * iu.y;
    xu[v * 4 + 2] = b2 * iu.z; xu[v * 4 + 3] = b3 * iu.w;
#pragma unroll
    for (int j = 0; j < 4; ++j) {
      mg = fmaxf(mg, fabsf(xg[v * 4 + j]));
      mu = fmaxf(mu, fabsf(xu[v * 4 + j]));
    }
  }
#pragma unroll
  for (int off = 32; off > 0; off >>= 1) {
    mg = fmaxf(mg, __shfl_xor(mg, off));
    mu = fmaxf(mu, __shfl_xor(mu, off));
  }
  __shared__ float smg[4], smu[4];
  if ((tid & 63) == 0) { smg[tid >> 6] = mg; smu[tid >> 6] = mu; }
  __syncthreads();
  mg = fmaxf(fmaxf(smg[0], smg[1]), fmaxf(smg[2], smg[3]));
  mu = fmaxf(fmaxf(smu[0], smu[1]), fmaxf(smu[2], smu[3]));
  const float scg = fmaxf(mg / 127.0f, 1e-8f);  // true division, matches np
  const float scu = fmaxf(mu / 127.0f, 1e-8f);
  signed char og[16] __attribute__((aligned(16)));
  signed char ou[16] __attribute__((aligned(16)));
#pragma unroll
  for (int j = 0; j < 16; ++j) {
    og[j] = (signed char)(int)fminf(fmaxf(rintf(xg[j] / scg), -127.f), 127.f);
    ou[j] = (signed char)(int)fminf(fmaxf(rintf(xu[j] / scu), -127.f), 127.f);
  }
  *(i32x4*)(qg + (size_t)t * H + c0) = *(const i32x4*)og;
  *(i32x4*)(qu + (size_t)t * H + c0) = *(const i32x4*)ou;
  if (tid == 0) { sg[t] = scg; su[t] = scu; }
}

// ---------------- fused gate+up GEMM + SwiGLU -> inter (bf16 bits) ----------------
// Tile 256(M) x 128(N), BK=64, 512 threads (8 waves as 4Mx2N, 64x64 per wave).
// Triple-buffered LDS, counted vmcnt(6) (6 global_load_lds per K-tile), one
// raw s_barrier per K-tile. LDS chunk-XOR swizzle: phys_chunk = c ^ ((r>>1)&3)
// applied on the GLOBAL source (linear LDS dest) and on the ds_read address.
#define G1_STAGE(b, kk)                                                       \
  {                                                                           \
    _Pragma("unroll") for (int p = 0; p < 2; ++p) {                           \
      const int g = p * 512 + tid;                                            \
      const int r = g >> 2;                                                   \
      const int c = (g & 3) ^ ((r >> 1) & 3);                                 \
      const size_t so = (size_t)r * H + (kk) + c * 16;                        \
      async16(&Ag[b][g * 16], qg + rowbase_a + so);                           \
      async16(&Au[b][g * 16], qu + rowbase_a + so);                           \
    }                                                                         \
    {                                                                         \
      const int r2 = tid >> 2;                                                \
      const int c2 = (tid & 3) ^ ((r2 >> 1) & 3);                             \
      const size_t so2 = (size_t)r2 * H + (kk) + c2 * 16;                     \
      async16(&Bg[b][tid * 16], wg + rowbase_b + so2);                        \
      async16(&Bu[b][tid * 16], wu + rowbase_b + so2);                        \
    }                                                                         \
  }

__global__ __launch_bounds__(512, 2) void gemm1_kernel(
    const signed char* __restrict__ qg, const signed char* __restrict__ qu,
    const float* __restrict__ sg, const float* __restrict__ su,
    const signed char* __restrict__ wg, const signed char* __restrict__ wu,
    const float* __restrict__ swg, const float* __restrict__ swu,
    unsigned short* __restrict__ inter, int H, int I) {
  __shared__ signed char Ag[3][256 * 64] __attribute__((aligned(16)));
  __shared__ signed char Au[3][256 * 64] __attribute__((aligned(16)));
  __shared__ signed char Bg[3][128 * 64] __attribute__((aligned(16)));
  __shared__ signed char Bu[3][128 * 64] __attribute__((aligned(16)));
  const int tid = threadIdx.x;
  const int lane = tid & 63, wave = tid >> 6;
  const int row0 = blockIdx.x * 256, col0 = blockIdx.y * 128;
  const int wm = wave >> 1, wn = wave & 1;  // 4x2 wave grid, 64x64 per wave
  const int mrow = lane & 15, quad = lane >> 4;
  const int NT = H >> 6;
  const size_t rowbase_a = (size_t)row0 * H;
  const size_t rowbase_b = (size_t)col0 * H;

  // loop-invariant swizzled LDS read offsets
  int offA[4], offB[4];
#pragma unroll
  for (int i = 0; i < 4; ++i) {
    const int ra = wm * 64 + i * 16 + mrow;
    offA[i] = ra * 64 + ((quad ^ ((ra >> 1) & 3)) << 4);
    const int rb = wn * 64 + i * 16 + mrow;
    offB[i] = rb * 64 + ((quad ^ ((rb >> 1) & 3)) << 4);
  }

  i32x4 accG[4][4], accU[4][4];
#pragma unroll
  for (int i = 0; i < 4; ++i)
#pragma unroll
    for (int j = 0; j < 4; ++j) {
      accG[i][j] = i32x4{0, 0, 0, 0};
      accU[i][j] = i32x4{0, 0, 0, 0};
    }

  // prologue: tiles 0,1 in flight; wait for tile 0 only
  G1_STAGE(0, 0);
  G1_STAGE(1, 64);
  asm volatile("s_waitcnt vmcnt(6)" ::: "memory");
  BARRIER;

  int bc = 0, bs = 2;
  for (int kt = 0; kt < NT; ++kt) {
    if (kt + 2 < NT) G1_STAGE(bs, (kt + 2) << 6);

    i32x4 aG[4], aU[4], bG[4], bU[4];
#pragma unroll
    for (int i = 0; i < 4; ++i) {
      aG[i] = *(const i32x4*)(&Ag[bc][0] + offA[i]);
      aU[i] = *(const i32x4*)(&Au[bc][0] + offA[i]);
      bG[i] = *(const i32x4*)(&Bg[bc][0] + offB[i]);
      bU[i] = *(const i32x4*)(&Bu[bc][0] + offB[i]);
    }
    __builtin_amdgcn_s_setprio(1);
#pragma unroll
    for (int i = 0; i < 4; ++i)
#pragma unroll
      for (int j = 0; j < 4; ++j) {
        accG[i][j] = mfma_i8(aG[i], bG[j], accG[i][j]);
        accU[i][j] = mfma_i8(aU[i], bU[j], accU[i][j]);
      }
    __builtin_amdgcn_s_setprio(0);

    if (kt + 2 < NT) {
      WAIT_VM6;  // tile kt+1 landed; tile kt+2's 6 loads stay in flight
      BARRIER;
    } else if (kt + 1 < NT) {
      WAIT_VM0;  // last in-flight tile
      BARRIER;
    }
    bc = (bc == 2) ? 0 : bc + 1;
    bs = (bs == 2) ? 0 : bs + 1;
  }

  // epilogue: dequant, silu(g)*u, clip +-10, bf16 RNE, store
  float swgc[4], swuc[4];
#pragma unroll
  for (int j = 0; j < 4; ++j) {
    const int c = col0 + wn * 64 + j * 16 + mrow;
    swgc[j] = swg[c];
    swuc[j] = swu[c];
  }
#pragma unroll
  for (int i = 0; i < 4; ++i) {
#pragma unroll
    for (int r = 0; r < 4; ++r) {
      const int row = row0 + wm * 64 + i * 16 + quad * 4 + r;
      const float sgr = sg[row], sur = su[row];
#pragma unroll
      for (int j = 0; j < 4; ++j) {
        const int c = col0 + wn * 64 + j * 16 + mrow;
        const float g = (float)accG[i][j][r] * sgr * swgc[j];
        const float u = (float)accU[i][j][r] * sur * swuc[j];
        const float sig = 1.f / (1.f + expf(-g));
        float v = (g * sig) * u;
        v = fminf(fmaxf(v, -10.f), 10.f);
        inter[(size_t)row * I + c] = bf16_bits(v);
      }
    }
  }
}

// ---------------- per-token quant of inter ----------------
__global__ __launch_bounds__(256) void quant_i_kernel(
    const unsigned short* __restrict__ inter, const float* __restrict__ invi,
    signed char* __restrict__ qi, float* __restrict__ si, int I) {
  const int t = blockIdx.x, tid = threadIdx.x;
  const unsigned short* ir = inter + (size_t)t * I;
  const int c0 = tid * 8;  // 256*8 = 2048 = I
  uint4 pk = *(const uint4*)(ir + c0);
  float4 i0 = *(const float4*)(invi + c0);
  float4 i1 = *(const float4*)(invi + c0 + 4);
  float xs[8];
  xs[0] = bf16_to_f(pk.x & 0xffffu) * i0.x;
  xs[1] = bf16_to_f(pk.x >> 16) * i0.y;
  xs[2] = bf16_to_f(pk.y & 0xffffu) * i0.z;
  xs[3] = bf16_to_f(pk.y >> 16) * i0.w;
  xs[4] = bf16_to_f(pk.z & 0xffffu) * i1.x;
  xs[5] = bf16_to_f(pk.z >> 16) * i1.y;
  xs[6] = bf16_to_f(pk.w & 0xffffu) * i1.z;
  xs[7] = bf16_to_f(pk.w >> 16) * i1.w;
  float m = 0.f;
#pragma unroll
  for (int j = 0; j < 8; ++j) m = fmaxf(m, fabsf(xs[j]));
#pragma unroll
  for (int off = 32; off > 0; off >>= 1) m = fmaxf(m, __shfl_xor(m, off));
  __shared__ float sm[4];
  if ((tid & 63) == 0) sm[tid >> 6] = m;
  __syncthreads();
  m = fmaxf(fmaxf(sm[0], sm[1]), fmaxf(sm[2], sm[3]));
  const float s = fmaxf(m / 127.0f, 1e-8f);
  signed char o[8] __attribute__((aligned(8)));
#pragma unroll
  for (int j = 0; j < 8; ++j)
    o[j] = (signed char)(int)fminf(fmaxf(rintf(xs[j] / s), -127.f), 127.f);
  *(unsigned long long*)(qi + (size_t)t * I + c0) = *(const unsigned long long*)o;
  if (tid == 0) si[t] = s;
}

// ---------------- down GEMM -> out fp32 ----------------
// Tile 256(M) x 256(N), BK=64, 512 threads (8 waves as 2Mx4N, 128x64 per wave).
// Same counted-vmcnt triple-buffer pipeline; 4 global_load_lds per K-tile.
#define G2_STAGE(b, kk)                                                       \
  {                                                                           \
    _Pragma("unroll") for (int p = 0; p < 2; ++p) {                           \
      const int g = p * 512 + tid;                                            \
      const int r = g >> 2;                                                   \
      const int c = (g & 3) ^ ((r >> 1) & 3);                                 \
      const size_t so = (size_t)r * I + (kk) + c * 16;                        \
      async16(&As[b][g * 16], qi + rowbase_a + so);                           \
      async16(&Bs[b][g * 16], wd + rowbase_b + so);                           \
    }                                                                         \
  }

__global__ __launch_bounds__(512, 2) void gemm2_kernel(
    const signed char* __restrict__ qi, const float* __restrict__ si,
    const signed char* __restrict__ wd, const float* __restrict__ swd,
    float* __restrict__ out, int H, int I) {
  __shared__ signed char As[3][256 * 64] __attribute__((aligned(16)));
  __shared__ signed char Bs[3][256 * 64] __attribute__((aligned(16)));
  const int tid = threadIdx.x;
  const int lane = tid & 63, wave = tid >> 6;
  const int row0 = blockIdx.x * 256, col0 = blockIdx.y * 256;
  const int wm = wave >> 2, wn = wave & 3;  // 2x4 wave grid, 128x64 per wave
  const int mrow = lane & 15, quad = lane >> 4;
  const int NT = I >> 6;
  const size_t rowbase_a = (size_t)row0 * I;
  const size_t rowbase_b = (size_t)col0 * I;

  int offA[8], offB[4];
#pragma unroll
  for (int i = 0; i < 8; ++i) {
    const int ra = wm * 128 + i * 16 + mrow;
    offA[i] = ra * 64 + ((quad ^ ((ra >> 1) & 3)) << 4);
  }
#pragma unroll
  for (int j = 0; j < 4; ++j) {
    const int rb = wn * 64 + j * 16 + mrow;
    offB[j] = rb * 64 + ((quad ^ ((rb >> 1) & 3)) << 4);
  }

  i32x4 acc[8][4];
#pragma unroll
  for (int i = 0; i < 8; ++i)
#pragma unroll
    for (int j = 0; j < 4; ++j) acc[i][j] = i32x4{0, 0, 0, 0};

  G2_STAGE(0, 0);
  G2_STAGE(1, 64);
  asm volatile("s_waitcnt vmcnt(4)" ::: "memory");
  BARRIER;

  int bc = 0, bs = 2;
  for (int kt = 0; kt < NT; ++kt) {
    if (kt + 2 < NT) G2_STAGE(bs, (kt + 2) << 6);

    i32x4 a[8], b[4];
#pragma unroll
    for (int i = 0; i < 8; ++i) a[i] = *(const i32x4*)(&As[bc][0] + offA[i]);
#pragma unroll
    for (int j = 0; j < 4; ++j) b[j] = *(const i32x4*)(&Bs[bc][0] + offB[j]);

    __builtin_amdgcn_s_setprio(1);
#pragma unroll
    for (int i = 0; i < 8; ++i)
#pragma unroll
      for (int j = 0; j < 4; ++j) acc[i][j] = mfma_i8(a[i], b[j], acc[i][j]);
    __builtin_amdgcn_s_setprio(0);

    if (kt + 2 < NT) {
      WAIT_VM4;
      BARRIER;
    } else if (kt + 1 < NT) {
      WAIT_VM0;
      BARRIER;
    }
    bc = (bc == 2) ? 0 : bc + 1;
    bs = (bs == 2) ? 0 : bs + 1;
  }

  float swc[4];
#pragma unroll
  for (int j = 0; j < 4; ++j) swc[j] = swd[col0 + wn * 64 + j * 16 + mrow];
#pragma unroll
  for (int i = 0; i < 8; ++i) {
#pragma unroll
    for (int r = 0; r < 4; ++r) {
      const int row = row0 + wm * 128 + i * 16 + quad * 4 + r;
      const float sir = si[row];
#pragma unroll
      for (int j = 0; j < 4; ++j) {
        const int c = col0 + wn * 64 + j * 16 + mrow;
        out[(size_t)row * H + c] = (float)acc[i][j][r] * sir * swc[j];
      }
    }
  }
}

extern "C" void kernel_launch(void* const* d_in, const int* in_sizes, int n_in,
                              void* d_out, int out_size, void* d_ws,
                              size_t ws_size, hipStream_t stream) {
  const float* x = (const float*)d_in[0];
  const float* w_gate = (const float*)d_in[1];
  const float* s_wgate = (const float*)d_in[2];
  const float* w_up = (const float*)d_in[3];
  const float* s_wup = (const float*)d_in[4];
  const float* w_down = (const float*)d_in[5];
  const float* s_wdown = (const float*)d_in[6];
  const float* inv_gate = (const float*)d_in[7];
  const float* inv_up = (const float*)d_in[8];
  const float* inv_inter = (const float*)d_in[9];
  float* out = (float*)d_out;

  const int H = in_sizes[6];          // 4096
  const int I = in_sizes[2];          // 2048
  const int T = in_sizes[0] / H;      // 8192

  char* ws = (char*)d_ws;
  size_t off = 0;
  signed char* wqg = (signed char*)(ws + off); off += (size_t)I * H;
  signed char* wqu = (signed char*)(ws + off); off += (size_t)I * H;
  signed char* wqd = (signed char*)(ws + off); off += (size_t)H * I;
  signed char* qg  = (signed char*)(ws + off); off += (size_t)T * H;
  signed char* qu  = (signed char*)(ws + off); off += (size_t)T * H;
  unsigned short* inter = (unsigned short*)(ws + off); off += (size_t)T * I * 2;
  float* sg = (float*)(ws + off); off += (size_t)T * 4;
  float* su = (float*)(ws + off); off += (size_t)T * 4;
  float* si = (float*)(ws + off); off += (size_t)T * 4;
  signed char* qi = qg;  // qg is dead after gemm1; reuse for qi

  const int nW = I * H;
  wconv_kernel<<<nW / 1024, 256, 0, stream>>>(w_gate, wqg, nW);
  wconv_kernel<<<nW / 1024, 256, 0, stream>>>(w_up, wqu, nW);
  wconv_kernel<<<nW / 1024, 256, 0, stream>>>(w_down, wqd, nW);

  quant_x_kernel<<<T, 256, 0, stream>>>(x, inv_gate, inv_up, qg, qu, sg, su, H);

  dim3 g1(T / 256, I / 128);
  gemm1_kernel<<<g1, 512, 0, stream>>>(qg, qu, sg, su, wqg, wqu, s_wgate,
                                       s_wup, inter, H, I);

  quant_i_kernel<<<T, 256, 0, stream>>>(inter, inv_inter, qi, si, I);

  dim3 g2(T / 256, H / 256);
  gemm2_kernel<<<g2, 512, 0, stream>>>(qi, si, wqd, s_wdown, out, H, I);
}